// Round 1
// baseline (174.149 us; speedup 1.0000x reference)
//
#include <hip/hip_runtime.h>

#define IMG_H 1024
#define IMG_W 1024
#define NIMG  16
#define RAD   5
#define KW    11
#define TX    32
#define TY    32
#define IN_W  (TX + 2*RAD)   // 42
#define IN_H  (TY + 2*RAD)   // 42
#define LDS_STRIDE 44
#define NPIX  (NIMG * IMG_H * IMG_W)   // 16777216

// Gaussian(sigma=1.5, 11 taps), normalized — matches np.exp(...)/sum in fp32.
__device__ __forceinline__ float gw(int k) {
    constexpr float G[KW] = {
        0.00102838f, 0.00759876f, 0.03600077f, 0.10936070f, 0.21300554f,
        0.26601173f,
        0.21300554f, 0.10936070f, 0.03600077f, 0.00759876f, 0.00102838f};
    return G[k];
}

__global__ __launch_bounds__(256) void ssim_tile_kernel(
        const float* __restrict__ img1, const float* __restrict__ img2,
        float* __restrict__ partial, int atomic_mode) {
    __shared__ float s1[IN_H][LDS_STRIDE];
    __shared__ float s2[IN_H][LDS_STRIDE];
    __shared__ float hb[5][IN_H][TX];   // h-blurred: x, y, x*x, y*y, x*y

    const int t = threadIdx.x;
    const int tile_x = blockIdx.x * TX;
    const int tile_y = blockIdx.y * TY;
    const float* p1 = img1 + (size_t)blockIdx.z * IMG_H * IMG_W;
    const float* p2 = img2 + (size_t)blockIdx.z * IMG_H * IMG_W;

    // ---- load 42x42 halo tile of both images (zero-padded at borders) ----
    for (int i = t; i < IN_H * IN_W; i += 256) {
        int r = i / IN_W, c = i % IN_W;
        int gr = tile_y + r - RAD, gc = tile_x + c - RAD;
        float v1 = 0.f, v2 = 0.f;
        if (gr >= 0 && gr < IMG_H && gc >= 0 && gc < IMG_W) {
            size_t off = (size_t)gr * IMG_W + gc;
            v1 = p1[off];
            v2 = p2[off];
        }
        s1[r][c] = v1;
        s2[r][c] = v2;
    }
    __syncthreads();

    // ---- horizontal blur of 5 quantities: 42 rows x 32 cols ----
    for (int i = t; i < IN_H * TX; i += 256) {
        int r = i / TX, c = i % TX;
        float a1 = 0.f, a2 = 0.f, a11 = 0.f, a22 = 0.f, a12 = 0.f;
#pragma unroll
        for (int k = 0; k < KW; ++k) {
            float x = s1[r][c + k];
            float y = s2[r][c + k];
            float g = gw(k);
            float gx = g * x;
            float gy = g * y;
            a1 += gx;
            a2 += gy;
            a11 = fmaf(gx, x, a11);
            a22 = fmaf(gy, y, a22);
            a12 = fmaf(gx, y, a12);
        }
        hb[0][r][c] = a1;
        hb[1][r][c] = a2;
        hb[2][r][c] = a11;
        hb[3][r][c] = a22;
        hb[4][r][c] = a12;
    }
    __syncthreads();

    // ---- vertical blur + SSIM formula + local accumulate ----
    const float C1 = 0.0001f;   // 0.01^2
    const float C2 = 0.0009f;   // 0.03^2
    float lsum = 0.f;
    for (int i = t; i < TY * TX; i += 256) {
        int r = i / TX, c = i % TX;
        float m1 = 0.f, m2 = 0.f, b11 = 0.f, b22 = 0.f, b12 = 0.f;
#pragma unroll
        for (int k = 0; k < KW; ++k) {
            float g = gw(k);
            m1  = fmaf(g, hb[0][r + k][c], m1);
            m2  = fmaf(g, hb[1][r + k][c], m2);
            b11 = fmaf(g, hb[2][r + k][c], b11);
            b22 = fmaf(g, hb[3][r + k][c], b22);
            b12 = fmaf(g, hb[4][r + k][c], b12);
        }
        float m1s = m1 * m1;
        float m2s = m2 * m2;
        float m12 = m1 * m2;
        float s1q = b11 - m1s;
        float s2q = b22 - m2s;
        float s12 = b12 - m12;
        float num = (2.f * m12 + C1) * (2.f * s12 + C2);
        float den = (m1s + m2s + C1) * (s1q + s2q + C2);
        lsum += num / den;
    }

    // ---- block reduction (4 waves of 64) ----
#pragma unroll
    for (int off = 32; off > 0; off >>= 1)
        lsum += __shfl_down(lsum, off, 64);
    __shared__ float wsum[4];
    if ((t & 63) == 0) wsum[t >> 6] = lsum;
    __syncthreads();
    if (t == 0) {
        float s = wsum[0] + wsum[1] + wsum[2] + wsum[3];
        if (atomic_mode) {
            atomicAdd(partial, s);
        } else {
            int bid = (blockIdx.z * gridDim.y + blockIdx.y) * gridDim.x + blockIdx.x;
            partial[bid] = s;
        }
    }
}

__global__ __launch_bounds__(256) void ssim_reduce_kernel(
        const float* __restrict__ partial, int n, float* __restrict__ out) {
    float s = 0.f;
    for (int i = threadIdx.x; i < n; i += 256) s += partial[i];
#pragma unroll
    for (int off = 32; off > 0; off >>= 1)
        s += __shfl_down(s, off, 64);
    __shared__ float ws[4];
    if ((threadIdx.x & 63) == 0) ws[threadIdx.x >> 6] = s;
    __syncthreads();
    if (threadIdx.x == 0) {
        float tot = ws[0] + ws[1] + ws[2] + ws[3];
        out[0] = 1.f - tot / (float)NPIX;
    }
}

extern "C" void kernel_launch(void* const* d_in, const int* in_sizes, int n_in,
                              void* d_out, int out_size, void* d_ws, size_t ws_size,
                              hipStream_t stream) {
    const float* img1 = (const float*)d_in[0];
    const float* img2 = (const float*)d_in[1];
    float* out = (float*)d_out;
    float* partial = (float*)d_ws;

    dim3 grid(IMG_W / TX, IMG_H / TY, NIMG);   // 32 x 32 x 16 = 16384 blocks
    const int nblocks = (IMG_W / TX) * (IMG_H / TY) * NIMG;
    const size_t needed = (size_t)nblocks * sizeof(float);

    if (ws_size >= needed) {
        // deterministic two-stage reduction
        ssim_tile_kernel<<<grid, 256, 0, stream>>>(img1, img2, partial, 0);
        ssim_reduce_kernel<<<1, 256, 0, stream>>>(partial, nblocks, out);
    } else {
        // fallback: single-float atomic accumulate in ws
        hipMemsetAsync(d_ws, 0, sizeof(float), stream);
        ssim_tile_kernel<<<grid, 256, 0, stream>>>(img1, img2, partial, 1);
        ssim_reduce_kernel<<<1, 256, 0, stream>>>(partial, 1, out);
    }
}

// Round 2
// 141.731 us; speedup vs baseline: 1.2287x; 1.2287x over previous
//
#include <hip/hip_runtime.h>

#define IMG_H 1024
#define IMG_W 1024
#define NIMG  16
#define RAD   5
#define KW    11
#define TX    32            // output tile width
#define TY    64            // output tile height
#define SROWS (TY + 2*RAD)  // 74 halo rows
#define SSTR  48            // s-tile row stride in floats (covers [tile_x-8, tile_x+40))
#define NPIX  (NIMG * IMG_H * IMG_W)

// Gaussian(sigma=1.5, 11 taps), normalized fp32 — matches reference window.
__device__ __forceinline__ float gw(int k) {
    constexpr float G[KW] = {
        0.00102838f, 0.00759876f, 0.03600077f, 0.10936070f, 0.21300554f,
        0.26601173f,
        0.21300554f, 0.10936070f, 0.03600077f, 0.00759876f, 0.00102838f};
    return G[k];
}

__global__ __launch_bounds__(256) void ssim_tile_kernel(
        const float* __restrict__ img1, const float* __restrict__ img2,
        float* __restrict__ partial, int atomic_mode) {
    // s col 0 <-> global col tile_x - 8  (16B aligned both sides)
    __shared__ float s1[SROWS][SSTR];
    __shared__ float s2[SROWS][SSTR];
    __shared__ float hb[5][SROWS][TX];   // h-blurred: x, y, xx, yy, xy

    const int t = threadIdx.x;
    const int tile_x = blockIdx.x * TX;
    const int tile_y = blockIdx.y * TY;
    const float* p1 = img1 + (size_t)blockIdx.z * IMG_H * IMG_W;
    const float* p2 = img2 + (size_t)blockIdx.z * IMG_H * IMG_W;

    // ---- phase 1: load halo tile, float4 ----
    // 74 rows x 12 float4 per row per image
    for (int i = t; i < SROWS * 12; i += 256) {
        int r = i / 12, c4 = i % 12;
        int gr = tile_y + r - RAD;
        int gc = tile_x + c4 * 4 - 8;
        float4 v1 = make_float4(0.f, 0.f, 0.f, 0.f);
        float4 v2 = make_float4(0.f, 0.f, 0.f, 0.f);
        if ((unsigned)gr < (unsigned)IMG_H) {
            if (gc >= 0 && gc + 3 < IMG_W) {
                const size_t off = (size_t)gr * IMG_W + gc;
                v1 = *reinterpret_cast<const float4*>(p1 + off);
                v2 = *reinterpret_cast<const float4*>(p2 + off);
            } else {
                float* e1 = &v1.x;
                float* e2 = &v2.x;
#pragma unroll
                for (int j = 0; j < 4; ++j) {
                    int g = gc + j;
                    if ((unsigned)g < (unsigned)IMG_W) {
                        size_t off = (size_t)gr * IMG_W + g;
                        e1[j] = p1[off];
                        e2[j] = p2[off];
                    }
                }
            }
        }
        *reinterpret_cast<float4*>(&s1[r][c4 * 4]) = v1;
        *reinterpret_cast<float4*>(&s2[r][c4 * 4]) = v2;
    }
    __syncthreads();

    // ---- phase 2: horizontal blur, 4 cols per unit, b128 LDS IO ----
    // output col c (0..31) <-> s col c+8; unit (r, g4): cols 4g4..4g4+3
    // taps need s cols [4g4+3, 4g4+16] ⊂ aligned window [4g4, 4g4+20)
    for (int u = t; u < SROWS * 8; u += 256) {
        int r = u >> 3, g4 = u & 7;
        float f1[20], f2[20];
#pragma unroll
        for (int w = 0; w < 5; ++w) {
            *reinterpret_cast<float4*>(&f1[w * 4]) =
                *reinterpret_cast<const float4*>(&s1[r][g4 * 4 + w * 4]);
            *reinterpret_cast<float4*>(&f2[w * 4]) =
                *reinterpret_cast<const float4*>(&s2[r][g4 * 4 + w * 4]);
        }
        float a0[4] = {}, a1[4] = {}, a2[4] = {}, a3[4] = {}, a4[4] = {};
#pragma unroll
        for (int k = 0; k < KW; ++k) {
            float g = gw(k);
#pragma unroll
            for (int j = 0; j < 4; ++j) {
                float x = f1[j + 3 + k];
                float y = f2[j + 3 + k];
                float gx = g * x;
                float gy = g * y;
                a0[j] += gx;
                a1[j] += gy;
                a2[j] = fmaf(gx, x, a2[j]);
                a3[j] = fmaf(gy, y, a3[j]);
                a4[j] = fmaf(gx, y, a4[j]);
            }
        }
        *reinterpret_cast<float4*>(&hb[0][r][g4 * 4]) = *reinterpret_cast<float4*>(a0);
        *reinterpret_cast<float4*>(&hb[1][r][g4 * 4]) = *reinterpret_cast<float4*>(a1);
        *reinterpret_cast<float4*>(&hb[2][r][g4 * 4]) = *reinterpret_cast<float4*>(a2);
        *reinterpret_cast<float4*>(&hb[3][r][g4 * 4]) = *reinterpret_cast<float4*>(a3);
        *reinterpret_cast<float4*>(&hb[4][r][g4 * 4]) = *reinterpret_cast<float4*>(a4);
    }
    __syncthreads();

    // ---- phase 3: vertical blur + SSIM, 4 cols x 2 rows per thread ----
    const int g4 = t & 7;          // column group
    const int rr = t >> 3;         // 0..31 -> output rows 2rr, 2rr+1
    float acc[5][2][4] = {};
#pragma unroll
    for (int q = 0; q < 5; ++q) {
#pragma unroll
        for (int k = 0; k < KW + 1; ++k) {
            float4 h = *reinterpret_cast<float4*>(&hb[q][2 * rr + k][g4 * 4]);
            const float* he = &h.x;
            if (k < KW) {
                float g = gw(k);
#pragma unroll
                for (int j = 0; j < 4; ++j)
                    acc[q][0][j] = fmaf(g, he[j], acc[q][0][j]);
            }
            if (k > 0) {
                float g = gw(k - 1);
#pragma unroll
                for (int j = 0; j < 4; ++j)
                    acc[q][1][j] = fmaf(g, he[j], acc[q][1][j]);
            }
        }
    }

    const float C1 = 0.0001f;
    const float C2 = 0.0009f;
    float lsum = 0.f;
#pragma unroll
    for (int rl = 0; rl < 2; ++rl) {
#pragma unroll
        for (int j = 0; j < 4; ++j) {
            float m1 = acc[0][rl][j];
            float m2 = acc[1][rl][j];
            float b11 = acc[2][rl][j];
            float b22 = acc[3][rl][j];
            float b12 = acc[4][rl][j];
            float m1s = m1 * m1;
            float m2s = m2 * m2;
            float m12 = m1 * m2;
            float num = (2.f * m12 + C1) * (2.f * (b12 - m12) + C2);
            float den = (m1s + m2s + C1) * ((b11 - m1s) + (b22 - m2s) + C2);
            lsum += num / den;
        }
    }

    // ---- block reduction ----
#pragma unroll
    for (int off = 32; off > 0; off >>= 1)
        lsum += __shfl_down(lsum, off, 64);
    __shared__ float wsum[4];
    if ((t & 63) == 0) wsum[t >> 6] = lsum;
    __syncthreads();
    if (t == 0) {
        float s = wsum[0] + wsum[1] + wsum[2] + wsum[3];
        if (atomic_mode) {
            atomicAdd(partial, s);
        } else {
            int bid = (blockIdx.z * gridDim.y + blockIdx.y) * gridDim.x + blockIdx.x;
            partial[bid] = s;
        }
    }
}

__global__ __launch_bounds__(256) void ssim_reduce_kernel(
        const float* __restrict__ partial, int n, float* __restrict__ out) {
    float s = 0.f;
    for (int i = threadIdx.x; i < n; i += 256) s += partial[i];
#pragma unroll
    for (int off = 32; off > 0; off >>= 1)
        s += __shfl_down(s, off, 64);
    __shared__ float ws[4];
    if ((threadIdx.x & 63) == 0) ws[threadIdx.x >> 6] = s;
    __syncthreads();
    if (threadIdx.x == 0) {
        float tot = ws[0] + ws[1] + ws[2] + ws[3];
        out[0] = 1.f - tot / (float)NPIX;
    }
}

extern "C" void kernel_launch(void* const* d_in, const int* in_sizes, int n_in,
                              void* d_out, int out_size, void* d_ws, size_t ws_size,
                              hipStream_t stream) {
    const float* img1 = (const float*)d_in[0];
    const float* img2 = (const float*)d_in[1];
    float* out = (float*)d_out;
    float* partial = (float*)d_ws;

    dim3 grid(IMG_W / TX, IMG_H / TY, NIMG);   // 32 x 16 x 16 = 8192 blocks
    const int nblocks = (IMG_W / TX) * (IMG_H / TY) * NIMG;
    const size_t needed = (size_t)nblocks * sizeof(float);

    if (ws_size >= needed) {
        ssim_tile_kernel<<<grid, 256, 0, stream>>>(img1, img2, partial, 0);
        ssim_reduce_kernel<<<1, 256, 0, stream>>>(partial, nblocks, out);
    } else {
        hipMemsetAsync(d_ws, 0, sizeof(float), stream);
        ssim_tile_kernel<<<grid, 256, 0, stream>>>(img1, img2, partial, 1);
        ssim_reduce_kernel<<<1, 256, 0, stream>>>(partial, 1, out);
    }
}

// Round 3
// 132.054 us; speedup vs baseline: 1.3188x; 1.0733x over previous
//
#include <hip/hip_runtime.h>

#define IMG_H 1024
#define IMG_W 1024
#define NIMG  16
#define RAD   5
#define KW    11
#define TX    32            // output tile width
#define TY    64            // output tile height
#define HROWS (TY + 2*RAD)  // 74 h-blurred halo rows
#define NPIX  (NIMG * IMG_H * IMG_W)

// Gaussian(sigma=1.5, 11 taps), normalized fp32 — matches reference window.
__device__ __forceinline__ float gw(int k) {
    constexpr float G[KW] = {
        0.00102838f, 0.00759876f, 0.03600077f, 0.10936070f, 0.21300554f,
        0.26601173f,
        0.21300554f, 0.10936070f, 0.03600077f, 0.00759876f, 0.00102838f};
    return G[k];
}

__global__ __launch_bounds__(256) void ssim_tile_kernel(
        const float* __restrict__ img1, const float* __restrict__ img2,
        float* __restrict__ partial, int atomic_mode) {
    // hb[q][row][slot*4 .. slot*4+3], f4-slot XOR-swizzled by row (T2/m201):
    // phys_slot = logical_slot ^ (row & 7). 47.4 KB -> 3 blocks/CU.
    __shared__ float hb[5][HROWS][TX];

    const int t = threadIdx.x;
    const int tile_x = blockIdx.x * TX;
    const int tile_y = blockIdx.y * TY;
    const size_t img_off = (size_t)blockIdx.z * (IMG_H * IMG_W);
    const float* p1 = img1 + img_off;
    const float* p2 = img2 + img_off;

    // ---- Phase A: horizontal blur of 5 quantities, direct from global ----
    // unit u = (halo row r, col-group g4): output cols tile_x+4*g4 .. +3
    // window: 20 aligned floats starting at global col tile_x + 4*g4 - 8
    for (int u = t; u < HROWS * 8; u += 256) {
        const int r = u >> 3, g4 = u & 7;
        const int gr = tile_y + r - RAD;
        const int gc0 = tile_x + g4 * 4 - 8;
        const bool rowok = ((unsigned)gr < (unsigned)IMG_H);
        const float* row1 = p1 + (size_t)gr * IMG_W;
        const float* row2 = p2 + (size_t)gr * IMG_W;
        float f1[20], f2[20];
#pragma unroll
        for (int w = 0; w < 5; ++w) {
            const int gc = gc0 + 4 * w;
            float4 a = make_float4(0.f, 0.f, 0.f, 0.f);
            float4 b = make_float4(0.f, 0.f, 0.f, 0.f);
            if (rowok) {
                if (gc >= 0 && gc <= IMG_W - 4) {
                    a = *reinterpret_cast<const float4*>(row1 + gc);
                    b = *reinterpret_cast<const float4*>(row2 + gc);
                } else if (gc > -4 && gc < IMG_W) {
                    float* ea = &a.x;
                    float* eb = &b.x;
#pragma unroll
                    for (int j = 0; j < 4; ++j) {
                        int g = gc + j;
                        if ((unsigned)g < (unsigned)IMG_W) {
                            ea[j] = row1[g];
                            eb[j] = row2[g];
                        }
                    }
                }
            }
            *reinterpret_cast<float4*>(&f1[4 * w]) = a;
            *reinterpret_cast<float4*>(&f2[4 * w]) = b;
        }
        float a0[4] = {}, a1[4] = {}, a2[4] = {}, a3[4] = {}, a4[4] = {};
#pragma unroll
        for (int k = 0; k < KW; ++k) {
            const float g = gw(k);
#pragma unroll
            for (int j = 0; j < 4; ++j) {
                float x = f1[j + 3 + k];
                float y = f2[j + 3 + k];
                float gx = g * x;
                float gy = g * y;
                a0[j] += gx;
                a1[j] += gy;
                a2[j] = fmaf(gx, x, a2[j]);
                a3[j] = fmaf(gy, y, a3[j]);
                a4[j] = fmaf(gx, y, a4[j]);
            }
        }
        const int ps = (g4 ^ (r & 7)) << 2;   // swizzled f4 slot -> float index
        *reinterpret_cast<float4*>(&hb[0][r][ps]) = *reinterpret_cast<float4*>(a0);
        *reinterpret_cast<float4*>(&hb[1][r][ps]) = *reinterpret_cast<float4*>(a1);
        *reinterpret_cast<float4*>(&hb[2][r][ps]) = *reinterpret_cast<float4*>(a2);
        *reinterpret_cast<float4*>(&hb[3][r][ps]) = *reinterpret_cast<float4*>(a3);
        *reinterpret_cast<float4*>(&hb[4][r][ps]) = *reinterpret_cast<float4*>(a4);
    }
    __syncthreads();

    // ---- Phase B: vertical blur + SSIM, 4 cols x 2 rows per thread ----
    const int g4 = t & 7;          // logical column slot
    const int rr = t >> 3;         // output rows 2rr, 2rr+1
    float acc[5][2][4] = {};
#pragma unroll
    for (int q = 0; q < 5; ++q) {
#pragma unroll
        for (int k = 0; k < KW + 1; ++k) {
            const int row = 2 * rr + k;
            const int ps = (g4 ^ (row & 7)) << 2;
            float4 h = *reinterpret_cast<const float4*>(&hb[q][row][ps]);
            const float* he = &h.x;
            if (k < KW) {
                const float g = gw(k);
#pragma unroll
                for (int j = 0; j < 4; ++j)
                    acc[q][0][j] = fmaf(g, he[j], acc[q][0][j]);
            }
            if (k > 0) {
                const float g = gw(k - 1);
#pragma unroll
                for (int j = 0; j < 4; ++j)
                    acc[q][1][j] = fmaf(g, he[j], acc[q][1][j]);
            }
        }
    }

    const float C1 = 0.0001f;
    const float C2 = 0.0009f;
    float lsum = 0.f;
#pragma unroll
    for (int rl = 0; rl < 2; ++rl) {
#pragma unroll
        for (int j = 0; j < 4; ++j) {
            float m1 = acc[0][rl][j];
            float m2 = acc[1][rl][j];
            float b11 = acc[2][rl][j];
            float b22 = acc[3][rl][j];
            float b12 = acc[4][rl][j];
            float m1s = m1 * m1;
            float m2s = m2 * m2;
            float m12 = m1 * m2;
            float num = (2.f * m12 + C1) * (2.f * (b12 - m12) + C2);
            float den = (m1s + m2s + C1) * ((b11 - m1s) + (b22 - m2s) + C2);
            lsum += num / den;
        }
    }

    // ---- block reduction ----
#pragma unroll
    for (int off = 32; off > 0; off >>= 1)
        lsum += __shfl_down(lsum, off, 64);
    __shared__ float wsum[4];
    if ((t & 63) == 0) wsum[t >> 6] = lsum;
    __syncthreads();
    if (t == 0) {
        float s = wsum[0] + wsum[1] + wsum[2] + wsum[3];
        if (atomic_mode) {
            atomicAdd(partial, s);
        } else {
            int bid = (blockIdx.z * gridDim.y + blockIdx.y) * gridDim.x + blockIdx.x;
            partial[bid] = s;
        }
    }
}

__global__ __launch_bounds__(256) void ssim_reduce_kernel(
        const float* __restrict__ partial, int n, float* __restrict__ out) {
    float s = 0.f;
    for (int i = threadIdx.x; i < n; i += 256) s += partial[i];
#pragma unroll
    for (int off = 32; off > 0; off >>= 1)
        s += __shfl_down(s, off, 64);
    __shared__ float ws[4];
    if ((threadIdx.x & 63) == 0) ws[threadIdx.x >> 6] = s;
    __syncthreads();
    if (threadIdx.x == 0) {
        float tot = ws[0] + ws[1] + ws[2] + ws[3];
        out[0] = 1.f - tot / (float)NPIX;
    }
}

extern "C" void kernel_launch(void* const* d_in, const int* in_sizes, int n_in,
                              void* d_out, int out_size, void* d_ws, size_t ws_size,
                              hipStream_t stream) {
    const float* img1 = (const float*)d_in[0];
    const float* img2 = (const float*)d_in[1];
    float* out = (float*)d_out;
    float* partial = (float*)d_ws;

    dim3 grid(IMG_W / TX, IMG_H / TY, NIMG);   // 32 x 16 x 16 = 8192 blocks
    const int nblocks = (IMG_W / TX) * (IMG_H / TY) * NIMG;
    const size_t needed = (size_t)nblocks * sizeof(float);

    if (ws_size >= needed) {
        ssim_tile_kernel<<<grid, 256, 0, stream>>>(img1, img2, partial, 0);
        ssim_reduce_kernel<<<1, 256, 0, stream>>>(partial, nblocks, out);
    } else {
        hipMemsetAsync(d_ws, 0, sizeof(float), stream);
        ssim_tile_kernel<<<grid, 256, 0, stream>>>(img1, img2, partial, 1);
        ssim_reduce_kernel<<<1, 256, 0, stream>>>(partial, 1, out);
    }
}

// Round 4
// 107.498 us; speedup vs baseline: 1.6200x; 1.2284x over previous
//
#include <hip/hip_runtime.h>
#include <hip/hip_fp16.h>

#define IMG_H 1024
#define IMG_W 1024
#define NIMG  16
#define RAD   5
#define KW    11
#define TX    64            // output tile width
#define TY    64            // output tile height
#define HROWS (TY + 2*RAD)  // 74 h-blurred halo rows
#define PADW  72            // hb row stride in halfs (144 B -> bank-phase spread)
#define NPIX  (NIMG * IMG_H * IMG_W)

// Gaussian(sigma=1.5, 11 taps), normalized fp32 — matches reference window.
__device__ __forceinline__ float gw(int k) {
    constexpr float G[KW] = {
        0.00102838f, 0.00759876f, 0.03600077f, 0.10936070f, 0.21300554f,
        0.26601173f,
        0.21300554f, 0.10936070f, 0.03600077f, 0.00759876f, 0.00102838f};
    return G[k];
}

__global__ __launch_bounds__(256, 3) void ssim_tile_kernel(
        const float* __restrict__ img1, const float* __restrict__ img2,
        float* __restrict__ partial, int atomic_mode) {
    // h-blurred quantities in fp16: x, y, xx, yy, xy. 53.3 KB -> 3 blocks/CU.
    __shared__ __align__(16) __half hb[5][HROWS][PADW];

    const int t = threadIdx.x;
    const int tile_x = blockIdx.x * TX;
    const int tile_y = blockIdx.y * TY;
    const size_t img_off = (size_t)blockIdx.z * (IMG_H * IMG_W);
    const float* p1 = img1 + img_off;
    const float* p2 = img2 + img_off;

    // ---- Phase A: horizontal blur of 5 quantities, direct from global ----
    // unit u = (halo row r, col-group g4 of 4): window = 20 aligned floats
    // starting at global col tile_x + 4*g4 - 8.
    for (int u = t; u < HROWS * 16; u += 256) {
        const int r = u >> 4, g4 = u & 15;
        const int gr = tile_y + r - RAD;
        const int gc0 = tile_x + g4 * 4 - 8;
        const bool rowok = ((unsigned)gr < (unsigned)IMG_H);
        const float* row1 = p1 + (size_t)gr * IMG_W;
        const float* row2 = p2 + (size_t)gr * IMG_W;
        float f1[20], f2[20];
#pragma unroll
        for (int w = 0; w < 5; ++w) {
            const int gc = gc0 + 4 * w;
            float4 a = make_float4(0.f, 0.f, 0.f, 0.f);
            float4 b = make_float4(0.f, 0.f, 0.f, 0.f);
            if (rowok) {
                if (gc >= 0 && gc <= IMG_W - 4) {
                    a = *reinterpret_cast<const float4*>(row1 + gc);
                    b = *reinterpret_cast<const float4*>(row2 + gc);
                } else if (gc > -4 && gc < IMG_W) {
                    float* ea = &a.x;
                    float* eb = &b.x;
#pragma unroll
                    for (int j = 0; j < 4; ++j) {
                        int g = gc + j;
                        if ((unsigned)g < (unsigned)IMG_W) {
                            ea[j] = row1[g];
                            eb[j] = row2[g];
                        }
                    }
                }
            }
            *reinterpret_cast<float4*>(&f1[4 * w]) = a;
            *reinterpret_cast<float4*>(&f2[4 * w]) = b;
        }
        float a0[4] = {}, a1[4] = {}, a2[4] = {}, a3[4] = {}, a4[4] = {};
#pragma unroll
        for (int k = 0; k < KW; ++k) {
            const float g = gw(k);
#pragma unroll
            for (int j = 0; j < 4; ++j) {
                float x = f1[j + 3 + k];
                float y = f2[j + 3 + k];
                float gx = g * x;
                float gy = g * y;
                a0[j] += gx;
                a1[j] += gy;
                a2[j] = fmaf(gx, x, a2[j]);
                a3[j] = fmaf(gy, y, a3[j]);
                a4[j] = fmaf(gx, y, a4[j]);
            }
        }
        // pack 4 fp32 -> 4 fp16, single 8B LDS store per quantity
        float* aq[5] = {a0, a1, a2, a3, a4};
#pragma unroll
        for (int q = 0; q < 5; ++q) {
            __half2 lo = __floats2half2_rn(aq[q][0], aq[q][1]);
            __half2 hi = __floats2half2_rn(aq[q][2], aq[q][3]);
            uint2 w2;
            w2.x = *reinterpret_cast<unsigned int*>(&lo);
            w2.y = *reinterpret_cast<unsigned int*>(&hi);
            *reinterpret_cast<uint2*>(&hb[q][r][g4 * 4]) = w2;
        }
    }
    __syncthreads();

    // ---- Phase B: vertical blur + SSIM, 8 cols x 2 rows per thread ----
    const int slot = t & 7;        // 8 slots x 8 cols = 64 cols
    const int rr = t >> 3;         // 0..31 -> output rows 2rr, 2rr+1
    float acc[5][2][8] = {};
#pragma unroll
    for (int q = 0; q < 5; ++q) {
#pragma unroll
        for (int k = 0; k < KW + 1; ++k) {
            const int row = 2 * rr + k;
            const uint4 rv = *reinterpret_cast<const uint4*>(&hb[q][row][slot * 8]);
            float f[8];
            {
                float2 t0 = __half22float2(*reinterpret_cast<const __half2*>(&rv.x));
                float2 t1 = __half22float2(*reinterpret_cast<const __half2*>(&rv.y));
                float2 t2 = __half22float2(*reinterpret_cast<const __half2*>(&rv.z));
                float2 t3 = __half22float2(*reinterpret_cast<const __half2*>(&rv.w));
                f[0] = t0.x; f[1] = t0.y; f[2] = t1.x; f[3] = t1.y;
                f[4] = t2.x; f[5] = t2.y; f[6] = t3.x; f[7] = t3.y;
            }
            if (k < KW) {
                const float g = gw(k);
#pragma unroll
                for (int j = 0; j < 8; ++j)
                    acc[q][0][j] = fmaf(g, f[j], acc[q][0][j]);
            }
            if (k > 0) {
                const float g = gw(k - 1);
#pragma unroll
                for (int j = 0; j < 8; ++j)
                    acc[q][1][j] = fmaf(g, f[j], acc[q][1][j]);
            }
        }
    }

    const float C1 = 0.0001f;
    const float C2 = 0.0009f;
    float lsum = 0.f;
#pragma unroll
    for (int rl = 0; rl < 2; ++rl) {
#pragma unroll
        for (int j = 0; j < 8; ++j) {
            float m1 = acc[0][rl][j];
            float m2 = acc[1][rl][j];
            float b11 = acc[2][rl][j];
            float b22 = acc[3][rl][j];
            float b12 = acc[4][rl][j];
            float m1s = m1 * m1;
            float m2s = m2 * m2;
            float m12 = m1 * m2;
            float num = (2.f * m12 + C1) * (2.f * (b12 - m12) + C2);
            float den = (m1s + m2s + C1) * ((b11 - m1s) + (b22 - m2s) + C2);
            lsum = fmaf(num, __builtin_amdgcn_rcpf(den), lsum);
        }
    }

    // ---- block reduction ----
#pragma unroll
    for (int off = 32; off > 0; off >>= 1)
        lsum += __shfl_down(lsum, off, 64);
    __shared__ float wsum[4];
    if ((t & 63) == 0) wsum[t >> 6] = lsum;
    __syncthreads();
    if (t == 0) {
        float s = wsum[0] + wsum[1] + wsum[2] + wsum[3];
        if (atomic_mode) {
            atomicAdd(partial, s);
        } else {
            int bid = (blockIdx.z * gridDim.y + blockIdx.y) * gridDim.x + blockIdx.x;
            partial[bid] = s;
        }
    }
}

__global__ __launch_bounds__(256) void ssim_reduce_kernel(
        const float* __restrict__ partial, int n, float* __restrict__ out) {
    float s = 0.f;
    for (int i = threadIdx.x; i < n; i += 256) s += partial[i];
#pragma unroll
    for (int off = 32; off > 0; off >>= 1)
        s += __shfl_down(s, off, 64);
    __shared__ float ws[4];
    if ((threadIdx.x & 63) == 0) ws[threadIdx.x >> 6] = s;
    __syncthreads();
    if (threadIdx.x == 0) {
        float tot = ws[0] + ws[1] + ws[2] + ws[3];
        out[0] = 1.f - tot / (float)NPIX;
    }
}

extern "C" void kernel_launch(void* const* d_in, const int* in_sizes, int n_in,
                              void* d_out, int out_size, void* d_ws, size_t ws_size,
                              hipStream_t stream) {
    const float* img1 = (const float*)d_in[0];
    const float* img2 = (const float*)d_in[1];
    float* out = (float*)d_out;
    float* partial = (float*)d_ws;

    dim3 grid(IMG_W / TX, IMG_H / TY, NIMG);   // 16 x 16 x 16 = 4096 blocks
    const int nblocks = (IMG_W / TX) * (IMG_H / TY) * NIMG;
    const size_t needed = (size_t)nblocks * sizeof(float);

    if (ws_size >= needed) {
        ssim_tile_kernel<<<grid, 256, 0, stream>>>(img1, img2, partial, 0);
        ssim_reduce_kernel<<<1, 256, 0, stream>>>(partial, nblocks, out);
    } else {
        hipMemsetAsync(d_ws, 0, sizeof(float), stream);
        ssim_tile_kernel<<<grid, 256, 0, stream>>>(img1, img2, partial, 1);
        ssim_reduce_kernel<<<1, 256, 0, stream>>>(partial, 1, out);
    }
}

// Round 5
// 107.225 us; speedup vs baseline: 1.6241x; 1.0025x over previous
//
#include <hip/hip_runtime.h>
#include <hip/hip_fp16.h>

#define IMG_H 1024
#define IMG_W 1024
#define NIMG  16
#define RAD   5
#define KW    11
#define TX    64            // output tile width
#define TY    64            // output tile height
#define HROWS (TY + 2*RAD)  // 74 h-blurred halo rows
#define PADW  72            // hb row stride in halfs (144 B -> bank-phase spread)
#define NPIX  (NIMG * IMG_H * IMG_W)

// Gaussian(sigma=1.5, 11 taps), normalized fp32 — matches reference window.
__device__ __forceinline__ float gw(int k) {
    constexpr float G[KW] = {
        0.00102838f, 0.00759876f, 0.03600077f, 0.10936070f, 0.21300554f,
        0.26601173f,
        0.21300554f, 0.10936070f, 0.03600077f, 0.00759876f, 0.00102838f};
    return G[k];
}

__global__ __launch_bounds__(256, 3) void ssim_tile_kernel(
        const float* __restrict__ img1, const float* __restrict__ img2,
        float* __restrict__ partial, int atomic_mode) {
    // h-blurred quantities in fp16: x, y, xx, yy, xy. 53.3 KB -> 3 blocks/CU.
    __shared__ __align__(16) __half hb[5][HROWS][PADW];

    const int t = threadIdx.x;
    const int tile_x = blockIdx.x * TX;
    const int tile_y = blockIdx.y * TY;
    const size_t img_off = (size_t)blockIdx.z * (IMG_H * IMG_W);
    const float* p1 = img1 + img_off;
    const float* p2 = img2 + img_off;

    // ---- Phase A: horizontal blur of 5 quantities, direct from global ----
    // unit u = (halo row r, col-group g4 of 4): window = 20 aligned floats
    // starting at global col tile_x + 4*g4 - 8.
    for (int u = t; u < HROWS * 16; u += 256) {
        const int r = u >> 4, g4 = u & 15;
        const int gr = tile_y + r - RAD;
        const int gc0 = tile_x + g4 * 4 - 8;
        const bool rowok = ((unsigned)gr < (unsigned)IMG_H);
        const float* row1 = p1 + (size_t)gr * IMG_W;
        const float* row2 = p2 + (size_t)gr * IMG_W;
        float f1[20], f2[20];
#pragma unroll
        for (int w = 0; w < 5; ++w) {
            const int gc = gc0 + 4 * w;
            float4 a = make_float4(0.f, 0.f, 0.f, 0.f);
            float4 b = make_float4(0.f, 0.f, 0.f, 0.f);
            if (rowok) {
                if (gc >= 0 && gc <= IMG_W - 4) {
                    a = *reinterpret_cast<const float4*>(row1 + gc);
                    b = *reinterpret_cast<const float4*>(row2 + gc);
                } else if (gc > -4 && gc < IMG_W) {
                    float* ea = &a.x;
                    float* eb = &b.x;
#pragma unroll
                    for (int j = 0; j < 4; ++j) {
                        int g = gc + j;
                        if ((unsigned)g < (unsigned)IMG_W) {
                            ea[j] = row1[g];
                            eb[j] = row2[g];
                        }
                    }
                }
            }
            *reinterpret_cast<float4*>(&f1[4 * w]) = a;
            *reinterpret_cast<float4*>(&f2[4 * w]) = b;
        }
        // share products across the 5 convolutions
        float xx[20], yy[20], xy[20];
#pragma unroll
        for (int i = 0; i < 20; ++i) {
            xx[i] = f1[i] * f1[i];
            yy[i] = f2[i] * f2[i];
            xy[i] = f1[i] * f2[i];
        }
        float a0[4] = {}, a1[4] = {}, a2[4] = {}, a3[4] = {}, a4[4] = {};
#pragma unroll
        for (int k = 0; k < KW; ++k) {
            const float g = gw(k);
#pragma unroll
            for (int j = 0; j < 4; ++j) {
                const int i = j + 3 + k;
                a0[j] = fmaf(g, f1[i], a0[j]);
                a1[j] = fmaf(g, f2[i], a1[j]);
                a2[j] = fmaf(g, xx[i], a2[j]);
                a3[j] = fmaf(g, yy[i], a3[j]);
                a4[j] = fmaf(g, xy[i], a4[j]);
            }
        }
        // pack 4 fp32 -> 4 fp16, single 8B LDS store per quantity
        float* aq[5] = {a0, a1, a2, a3, a4};
#pragma unroll
        for (int q = 0; q < 5; ++q) {
            __half2 lo = __floats2half2_rn(aq[q][0], aq[q][1]);
            __half2 hi = __floats2half2_rn(aq[q][2], aq[q][3]);
            uint2 w2;
            w2.x = *reinterpret_cast<unsigned int*>(&lo);
            w2.y = *reinterpret_cast<unsigned int*>(&hi);
            *reinterpret_cast<uint2*>(&hb[q][r][g4 * 4]) = w2;
        }
    }
    __syncthreads();

    // ---- Phase B: vertical blur (packed fp16) + SSIM, 8 cols x 2 rows ----
    const int slot = t & 7;        // 8 slots x 8 cols = 64 cols
    const int rr = t >> 3;         // 0..31 -> output rows 2rr, 2rr+1

    __half2 gh2[KW];
#pragma unroll
    for (int k = 0; k < KW; ++k) gh2[k] = __float2half2_rn(gw(k));

    __half2 acc[5][2][4];
#pragma unroll
    for (int q = 0; q < 5; ++q)
#pragma unroll
        for (int rl = 0; rl < 2; ++rl)
#pragma unroll
            for (int j = 0; j < 4; ++j)
                acc[q][rl][j] = __floats2half2_rn(0.f, 0.f);

#pragma unroll
    for (int q = 0; q < 5; ++q) {
#pragma unroll
        for (int k = 0; k < KW + 1; ++k) {
            const int row = 2 * rr + k;
            const uint4 rv = *reinterpret_cast<const uint4*>(&hb[q][row][slot * 8]);
            __half2 h[4];
            h[0] = *reinterpret_cast<const __half2*>(&rv.x);
            h[1] = *reinterpret_cast<const __half2*>(&rv.y);
            h[2] = *reinterpret_cast<const __half2*>(&rv.z);
            h[3] = *reinterpret_cast<const __half2*>(&rv.w);
            if (k < KW) {
#pragma unroll
                for (int j = 0; j < 4; ++j)
                    acc[q][0][j] = __hfma2(gh2[k], h[j], acc[q][0][j]);
            }
            if (k > 0) {
#pragma unroll
                for (int j = 0; j < 4; ++j)
                    acc[q][1][j] = __hfma2(gh2[k - 1], h[j], acc[q][1][j]);
            }
        }
    }

    const float C1 = 0.0001f;
    const float C2 = 0.0009f;
    float lsum = 0.f;
#pragma unroll
    for (int rl = 0; rl < 2; ++rl) {
#pragma unroll
        for (int j = 0; j < 4; ++j) {
            float2 m1p  = __half22float2(acc[0][rl][j]);
            float2 m2p  = __half22float2(acc[1][rl][j]);
            float2 b11p = __half22float2(acc[2][rl][j]);
            float2 b22p = __half22float2(acc[3][rl][j]);
            float2 b12p = __half22float2(acc[4][rl][j]);
#pragma unroll
            for (int e = 0; e < 2; ++e) {
                float m1 = e ? m1p.y : m1p.x;
                float m2 = e ? m2p.y : m2p.x;
                float b11 = e ? b11p.y : b11p.x;
                float b22 = e ? b22p.y : b22p.x;
                float b12 = e ? b12p.y : b12p.x;
                float m1s = m1 * m1;
                float m2s = m2 * m2;
                float m12 = m1 * m2;
                float num = (2.f * m12 + C1) * (2.f * (b12 - m12) + C2);
                float den = (m1s + m2s + C1) * ((b11 - m1s) + (b22 - m2s) + C2);
                lsum = fmaf(num, __builtin_amdgcn_rcpf(den), lsum);
            }
        }
    }

    // ---- block reduction ----
#pragma unroll
    for (int off = 32; off > 0; off >>= 1)
        lsum += __shfl_down(lsum, off, 64);
    __shared__ float wsum[4];
    if ((t & 63) == 0) wsum[t >> 6] = lsum;
    __syncthreads();
    if (t == 0) {
        float s = wsum[0] + wsum[1] + wsum[2] + wsum[3];
        if (atomic_mode) {
            atomicAdd(partial, s);
        } else {
            int bid = (blockIdx.z * gridDim.y + blockIdx.y) * gridDim.x + blockIdx.x;
            partial[bid] = s;
        }
    }
}

__global__ __launch_bounds__(256) void ssim_reduce_kernel(
        const float* __restrict__ partial, int n, float* __restrict__ out) {
    float s = 0.f;
    for (int i = threadIdx.x; i < n; i += 256) s += partial[i];
#pragma unroll
    for (int off = 32; off > 0; off >>= 1)
        s += __shfl_down(s, off, 64);
    __shared__ float ws[4];
    if ((threadIdx.x & 63) == 0) ws[threadIdx.x >> 6] = s;
    __syncthreads();
    if (threadIdx.x == 0) {
        float tot = ws[0] + ws[1] + ws[2] + ws[3];
        out[0] = 1.f - tot / (float)NPIX;
    }
}

extern "C" void kernel_launch(void* const* d_in, const int* in_sizes, int n_in,
                              void* d_out, int out_size, void* d_ws, size_t ws_size,
                              hipStream_t stream) {
    const float* img1 = (const float*)d_in[0];
    const float* img2 = (const float*)d_in[1];
    float* out = (float*)d_out;
    float* partial = (float*)d_ws;

    dim3 grid(IMG_W / TX, IMG_H / TY, NIMG);   // 16 x 16 x 16 = 4096 blocks
    const int nblocks = (IMG_W / TX) * (IMG_H / TY) * NIMG;
    const size_t needed = (size_t)nblocks * sizeof(float);

    if (ws_size >= needed) {
        ssim_tile_kernel<<<grid, 256, 0, stream>>>(img1, img2, partial, 0);
        ssim_reduce_kernel<<<1, 256, 0, stream>>>(partial, nblocks, out);
    } else {
        hipMemsetAsync(d_ws, 0, sizeof(float), stream);
        ssim_tile_kernel<<<grid, 256, 0, stream>>>(img1, img2, partial, 1);
        ssim_reduce_kernel<<<1, 256, 0, stream>>>(partial, 1, out);
    }
}

// Round 6
// 97.306 us; speedup vs baseline: 1.7897x; 1.1019x over previous
//
#include <hip/hip_runtime.h>
#include <hip/hip_fp16.h>

#define IMG_H 1024
#define IMG_W 1024
#define NIMG  16
#define RAD   5
#define KW    11
#define TX    64            // output tile width
#define TY    64            // output tile height
#define HROWS (TY + 2*RAD)  // 74 h-blurred halo rows
#define PADW  72            // hb row stride in halfs (144 B -> bank-phase spread)
#define AUNITS (HROWS * 16) // 1184 Phase-A units (4 cols each)
#define NPIX  (NIMG * IMG_H * IMG_W)

// Gaussian(sigma=1.5, 11 taps), normalized fp32 — matches reference window.
__device__ __forceinline__ float gw(int k) {
    constexpr float G[KW] = {
        0.00102838f, 0.00759876f, 0.03600077f, 0.10936070f, 0.21300554f,
        0.26601173f,
        0.21300554f, 0.10936070f, 0.03600077f, 0.00759876f, 0.00102838f};
    return G[k];
}

// 11-tap h-blur of 5 quantities over a 20-float window, 4 outputs.
__device__ __forceinline__ void hblur4(const float f1[20], const float f2[20],
                                       float a0[4], float a1[4], float a2[4],
                                       float a3[4], float a4[4]) {
#pragma unroll
    for (int k = 0; k < KW; ++k) {
        const float g = gw(k);
#pragma unroll
        for (int j = 0; j < 4; ++j) {
            float x = f1[j + 3 + k];
            float y = f2[j + 3 + k];
            float gx = g * x;
            float gy = g * y;
            a0[j] += gx;
            a1[j] += gy;
            a2[j] = fmaf(gx, x, a2[j]);
            a3[j] = fmaf(gy, y, a3[j]);
            a4[j] = fmaf(gx, y, a4[j]);
        }
    }
}

__global__ __launch_bounds__(256, 4) void ssim_tile_kernel(
        const float* __restrict__ img1, const float* __restrict__ img2,
        float* __restrict__ partial, int atomic_mode) {
    // h-blurred quantities in fp16: x, y, xx, yy, xy. 53.3 KB -> 3 blocks/CU.
    __shared__ __align__(16) __half hb[5][HROWS][PADW];

    const int t = threadIdx.x;
    const int tile_x = blockIdx.x * TX;
    const int tile_y = blockIdx.y * TY;
    const size_t img_off = (size_t)blockIdx.z * (IMG_H * IMG_W);
    const float* p1 = img1 + img_off;
    const float* p2 = img2 + img_off;

    // Interior test covers phantom units (u < 1280 -> r <= 79, gr <= tile_y+74;
    // also next-iter hoisted loads r <= 89 -> gr <= tile_y+84 <= 1023 for
    // tile_y <= 896). Branch-free Phase A for 76% of blocks.
    const bool interior =
        (tile_x >= 8) && (tile_x <= IMG_W - 80) &&
        (tile_y >= RAD) && (tile_y <= IMG_H - 128);

    if (interior) {
        // ---- Phase A fast path: fully unrolled, branch-free loads ----
#pragma unroll
        for (int i = 0; i < 5; ++i) {
            const int u = t + 256 * i;
            const int r = u >> 4, g4 = u & 15;
            const size_t base =
                (size_t)(tile_y + r - RAD) * IMG_W + (tile_x + g4 * 4 - 8);
            const float* b1 = p1 + base;
            const float* b2 = p2 + base;
            float f1[20], f2[20];
#pragma unroll
            for (int w = 0; w < 5; ++w) {
                *reinterpret_cast<float4*>(&f1[4 * w]) =
                    *reinterpret_cast<const float4*>(b1 + 4 * w);
                *reinterpret_cast<float4*>(&f2[4 * w]) =
                    *reinterpret_cast<const float4*>(b2 + 4 * w);
            }
            float a0[4] = {}, a1[4] = {}, a2[4] = {}, a3[4] = {}, a4[4] = {};
            hblur4(f1, f2, a0, a1, a2, a3, a4);
            if (u < AUNITS) {
                float* aq[5] = {a0, a1, a2, a3, a4};
#pragma unroll
                for (int q = 0; q < 5; ++q) {
                    __half2 lo = __floats2half2_rn(aq[q][0], aq[q][1]);
                    __half2 hi = __floats2half2_rn(aq[q][2], aq[q][3]);
                    uint2 w2;
                    w2.x = *reinterpret_cast<unsigned int*>(&lo);
                    w2.y = *reinterpret_cast<unsigned int*>(&hi);
                    *reinterpret_cast<uint2*>(&hb[q][r][g4 * 4]) = w2;
                }
            }
        }
    } else {
        // ---- Phase A boundary path: guarded loads ----
        for (int u = t; u < AUNITS; u += 256) {
            const int r = u >> 4, g4 = u & 15;
            const int gr = tile_y + r - RAD;
            const int gc0 = tile_x + g4 * 4 - 8;
            const bool rowok = ((unsigned)gr < (unsigned)IMG_H);
            const float* row1 = p1 + (size_t)gr * IMG_W;
            const float* row2 = p2 + (size_t)gr * IMG_W;
            float f1[20], f2[20];
#pragma unroll
            for (int w = 0; w < 5; ++w) {
                const int gc = gc0 + 4 * w;
                float4 a = make_float4(0.f, 0.f, 0.f, 0.f);
                float4 b = make_float4(0.f, 0.f, 0.f, 0.f);
                if (rowok) {
                    if (gc >= 0 && gc <= IMG_W - 4) {
                        a = *reinterpret_cast<const float4*>(row1 + gc);
                        b = *reinterpret_cast<const float4*>(row2 + gc);
                    } else if (gc > -4 && gc < IMG_W) {
                        float* ea = &a.x;
                        float* eb = &b.x;
#pragma unroll
                        for (int j = 0; j < 4; ++j) {
                            int g = gc + j;
                            if ((unsigned)g < (unsigned)IMG_W) {
                                ea[j] = row1[g];
                                eb[j] = row2[g];
                            }
                        }
                    }
                }
                *reinterpret_cast<float4*>(&f1[4 * w]) = a;
                *reinterpret_cast<float4*>(&f2[4 * w]) = b;
            }
            float a0[4] = {}, a1[4] = {}, a2[4] = {}, a3[4] = {}, a4[4] = {};
            hblur4(f1, f2, a0, a1, a2, a3, a4);
            float* aq[5] = {a0, a1, a2, a3, a4};
#pragma unroll
            for (int q = 0; q < 5; ++q) {
                __half2 lo = __floats2half2_rn(aq[q][0], aq[q][1]);
                __half2 hi = __floats2half2_rn(aq[q][2], aq[q][3]);
                uint2 w2;
                w2.x = *reinterpret_cast<unsigned int*>(&lo);
                w2.y = *reinterpret_cast<unsigned int*>(&hi);
                *reinterpret_cast<uint2*>(&hb[q][r][g4 * 4]) = w2;
            }
        }
    }
    __syncthreads();

    // ---- Phase B: vertical blur (packed fp16) + SSIM, 8 cols x 2 rows ----
    const int slot = t & 7;        // 8 slots x 8 cols = 64 cols
    const int rr = t >> 3;         // 0..31 -> output rows 2rr, 2rr+1

    __half2 gh2[KW];
#pragma unroll
    for (int k = 0; k < KW; ++k) gh2[k] = __float2half2_rn(gw(k));

    __half2 acc[5][2][4];
#pragma unroll
    for (int q = 0; q < 5; ++q)
#pragma unroll
        for (int rl = 0; rl < 2; ++rl)
#pragma unroll
            for (int j = 0; j < 4; ++j)
                acc[q][rl][j] = __floats2half2_rn(0.f, 0.f);

#pragma unroll
    for (int q = 0; q < 5; ++q) {
#pragma unroll
        for (int k = 0; k < KW + 1; ++k) {
            const int row = 2 * rr + k;
            const uint4 rv = *reinterpret_cast<const uint4*>(&hb[q][row][slot * 8]);
            __half2 h[4];
            h[0] = *reinterpret_cast<const __half2*>(&rv.x);
            h[1] = *reinterpret_cast<const __half2*>(&rv.y);
            h[2] = *reinterpret_cast<const __half2*>(&rv.z);
            h[3] = *reinterpret_cast<const __half2*>(&rv.w);
            if (k < KW) {
#pragma unroll
                for (int j = 0; j < 4; ++j)
                    acc[q][0][j] = __hfma2(gh2[k], h[j], acc[q][0][j]);
            }
            if (k > 0) {
#pragma unroll
                for (int j = 0; j < 4; ++j)
                    acc[q][1][j] = __hfma2(gh2[k - 1], h[j], acc[q][1][j]);
            }
        }
    }

    const float C1 = 0.0001f;
    const float C2 = 0.0009f;
    float lsum = 0.f;
#pragma unroll
    for (int rl = 0; rl < 2; ++rl) {
#pragma unroll
        for (int j = 0; j < 4; ++j) {
            float2 m1p  = __half22float2(acc[0][rl][j]);
            float2 m2p  = __half22float2(acc[1][rl][j]);
            float2 b11p = __half22float2(acc[2][rl][j]);
            float2 b22p = __half22float2(acc[3][rl][j]);
            float2 b12p = __half22float2(acc[4][rl][j]);
#pragma unroll
            for (int e = 0; e < 2; ++e) {
                float m1 = e ? m1p.y : m1p.x;
                float m2 = e ? m2p.y : m2p.x;
                float b11 = e ? b11p.y : b11p.x;
                float b22 = e ? b22p.y : b22p.x;
                float b12 = e ? b12p.y : b12p.x;
                float m1s = m1 * m1;
                float m2s = m2 * m2;
                float m12 = m1 * m2;
                float num = (2.f * m12 + C1) * (2.f * (b12 - m12) + C2);
                float den = (m1s + m2s + C1) * ((b11 - m1s) + (b22 - m2s) + C2);
                lsum = fmaf(num, __builtin_amdgcn_rcpf(den), lsum);
            }
        }
    }

    // ---- block reduction ----
#pragma unroll
    for (int off = 32; off > 0; off >>= 1)
        lsum += __shfl_down(lsum, off, 64);
    __shared__ float wsum[4];
    if ((t & 63) == 0) wsum[t >> 6] = lsum;
    __syncthreads();
    if (t == 0) {
        float s = wsum[0] + wsum[1] + wsum[2] + wsum[3];
        if (atomic_mode) {
            atomicAdd(partial, s);
        } else {
            int bid = (blockIdx.z * gridDim.y + blockIdx.y) * gridDim.x + blockIdx.x;
            partial[bid] = s;
        }
    }
}

__global__ __launch_bounds__(256) void ssim_reduce_kernel(
        const float* __restrict__ partial, int n, float* __restrict__ out) {
    float s = 0.f;
    for (int i = threadIdx.x; i < n; i += 256) s += partial[i];
#pragma unroll
    for (int off = 32; off > 0; off >>= 1)
        s += __shfl_down(s, off, 64);
    __shared__ float ws[4];
    if ((threadIdx.x & 63) == 0) ws[threadIdx.x >> 6] = s;
    __syncthreads();
    if (threadIdx.x == 0) {
        float tot = ws[0] + ws[1] + ws[2] + ws[3];
        out[0] = 1.f - tot / (float)NPIX;
    }
}

extern "C" void kernel_launch(void* const* d_in, const int* in_sizes, int n_in,
                              void* d_out, int out_size, void* d_ws, size_t ws_size,
                              hipStream_t stream) {
    const float* img1 = (const float*)d_in[0];
    const float* img2 = (const float*)d_in[1];
    float* out = (float*)d_out;
    float* partial = (float*)d_ws;

    dim3 grid(IMG_W / TX, IMG_H / TY, NIMG);   // 16 x 16 x 16 = 4096 blocks
    const int nblocks = (IMG_W / TX) * (IMG_H / TY) * NIMG;
    const size_t needed = (size_t)nblocks * sizeof(float);

    if (ws_size >= needed) {
        ssim_tile_kernel<<<grid, 256, 0, stream>>>(img1, img2, partial, 0);
        ssim_reduce_kernel<<<1, 256, 0, stream>>>(partial, nblocks, out);
    } else {
        hipMemsetAsync(d_ws, 0, sizeof(float), stream);
        ssim_tile_kernel<<<grid, 256, 0, stream>>>(img1, img2, partial, 1);
        ssim_reduce_kernel<<<1, 256, 0, stream>>>(partial, 1, out);
    }
}